// Round 1
// baseline (13839.844 us; speedup 1.0000x reference)
//
#include <hip/hip_runtime.h>

// LSTM scan, fused x@W_ih.T + h@W_hh.T via concat-K=1024 bf16 MFMA.
// 256 WGs = 4 batch-groups(64 batches) x 64 members(8 hidden units / 32 gate rows).
// W slice persistent in LDS in B-fragment order; h exchanged via d_ws with
// acquire/release step-counter flags (double buffer). State (c,h) in registers.

#define T_STEPS 256
#define BATCH   256
#define INP     512
#define HID     512
#define GROUPS  4
#define MEMB    64
#define BT      64          // batches per group
#define HS      8           // hidden units per member
#define NWG     (GROUPS*MEMB)
#define NTHR    256
#define LDS_BYTES (64*1024 + 2*BT*4)   // W frags (32768 ushort) + keeps[2][BT]

typedef float  f32x4  __attribute__((ext_vector_type(4)));
typedef short  bf16x8 __attribute__((ext_vector_type(8)));

__device__ __forceinline__ unsigned short f2bf(float f) {
  unsigned u = __builtin_bit_cast(unsigned, f);
  return (unsigned short)((u + 0x8000u) >> 16);   // round-half-up to bf16
}
__device__ __forceinline__ bf16x8 cvt8(float4 a, float4 b) {
  bf16x8 v;
  v[0]=(short)f2bf(a.x); v[1]=(short)f2bf(a.y); v[2]=(short)f2bf(a.z); v[3]=(short)f2bf(a.w);
  v[4]=(short)f2bf(b.x); v[5]=(short)f2bf(b.y); v[6]=(short)f2bf(b.z); v[7]=(short)f2bf(b.w);
  return v;
}
__device__ __forceinline__ float sigf(float x) {
  return __fdividef(1.0f, 1.0f + __expf(-x));
}
__device__ __forceinline__ float tanh_(float x) {
  float e = __expf(-2.0f * fabsf(x));
  float t = __fdividef(1.0f - e, 1.0f + e);
  return copysignf(t, x);
}
__device__ __forceinline__ f32x4 shflx4(f32x4 v, int m) {
  f32x4 r;
  r[0]=__shfl_xor(v[0],m,64); r[1]=__shfl_xor(v[1],m,64);
  r[2]=__shfl_xor(v[2],m,64); r[3]=__shfl_xor(v[3],m,64);
  return r;
}

__global__ void __launch_bounds__(NTHR, 2)
lstm_fused(const float* __restrict__ x, const int* __restrict__ dones,
           const float* __restrict__ Wih, const float* __restrict__ Whh,
           const float* __restrict__ bih, const float* __restrict__ bhh,
           float* __restrict__ out, unsigned short* __restrict__ hbuf,
           int* __restrict__ flags)
{
  extern __shared__ unsigned short smem[];   // [32768] W frags, then keeps
  float* kf = (float*)(smem + 32768);        // keeps[2][BT]

  const int tid  = threadIdx.x;
  const int lane = tid & 63;
  const int mt   = tid >> 6;              // wave id = M-tile (16 batches)
  const int grp  = blockIdx.x >> 6;
  const int memb = blockIdx.x & 63;
  const int b0   = grp * BT;
  const int j0   = memb * HS;
  const int q    = lane >> 4;
  const int n    = lane & 15;
  const int r    = lane & 7;

  // ---- one-time: W slice -> LDS, pre-packed in MFMA B-fragment order ----
  // slice row s in [0,32): gate g=s>>3, hidden r=s&7, global row g*512+j0+r
  // concat k in [0,1024): k<512 -> W_ih[.,k], else W_hh[.,k-512]
  for (int e = tid; e < 32*1024; e += NTHR) {
    int s = e >> 10, k = e & 1023;
    int g = s >> 3, rr = s & 7;
    int grow = g*HID + j0 + rr;
    float v = (k < INP) ? Wih[grow*INP + k] : Whh[grow*HID + (k - INP)];
    int kk = k >> 5, qq = (k >> 3) & 3, j = k & 7;
    int nt = s >> 4, nn = s & 15;
    smem[(((kk*2 + nt)*64) + qq*16 + nn)*8 + j] = f2bf(v);
  }
  if (tid < BT) kf[tid] = 1.0f - (float)dones[b0 + tid];   // keeps for t=0
  __syncthreads();

  // per-lane biases for hidden unit j0+r, gates i,f,g,o
  const float bi  = bih[0*HID + j0 + r] + bhh[0*HID + j0 + r];
  const float bf_ = bih[1*HID + j0 + r] + bhh[1*HID + j0 + r];
  const float bg  = bih[2*HID + j0 + r] + bhh[2*HID + j0 + r];
  const float bo  = bih[3*HID + j0 + r] + bhh[3*HID + j0 + r];

  float h_s[2] = {0.f, 0.f}, c_s[2] = {0.f, 0.f};
  const bool lo  = (n < 8);
  const int  rgb = lo ? 0 : 2;
  float* hidb = out + (size_t)T_STEPS*BATCH*HID;
  const int myflag = grp*MEMB + memb;
  const bf16x8 zfrag = {0,0,0,0,0,0,0,0};

  for (int t = 0; t < T_STEPS; ++t) {
    f32x4 acc0 = {0.f,0.f,0.f,0.f}, acc1 = {0.f,0.f,0.f,0.f};

    // ---- x part first: independent of peers, hides sync latency ----
    const float* xrow = x + (size_t)((t*BATCH) + b0 + mt*16 + n)*INP + q*8;
    #pragma unroll
    for (int kk = 0; kk < 16; ++kk) {
      float4 xa = *(const float4*)(xrow + kk*32);
      float4 xb = *(const float4*)(xrow + kk*32 + 4);
      bf16x8 a = cvt8(xa, xb);
      bf16x8 bA = *(const bf16x8*)(smem + ((kk*2+0)*64 + lane)*8);
      bf16x8 bB = *(const bf16x8*)(smem + ((kk*2+1)*64 + lane)*8);
      acc0 = __builtin_amdgcn_mfma_f32_16x16x32_bf16(a, bA, acc0, 0, 0, 0);
      acc1 = __builtin_amdgcn_mfma_f32_16x16x32_bf16(a, bB, acc1, 0, 0, 0);
    }

    // ---- wait for peers' h(t-1) ----
    if (t > 0) {
      int* fp = flags + grp*MEMB + lane;   // lane 0..63 = member id
      while (true) {
        int fv = __hip_atomic_load(fp, __ATOMIC_ACQUIRE, __HIP_MEMORY_SCOPE_AGENT);
        if (__all(fv >= t)) break;
        __builtin_amdgcn_s_sleep(2);
      }
    }

    // ---- h part: A rows masked by keep(t) ----
    const float kpA = kf[(t&1)*BT + mt*16 + n];
    const unsigned short* hrow =
        hbuf + ((t+1)&1)*(BATCH*HID) + (b0 + mt*16 + n)*HID + q*8;
    #pragma unroll
    for (int kk = 0; kk < 16; ++kk) {
      bf16x8 a = *(const bf16x8*)(hrow + kk*32);
      if (kpA == 0.0f) a = zfrag;
      int kg = 16 + kk;
      bf16x8 bA = *(const bf16x8*)(smem + ((kg*2+0)*64 + lane)*8);
      bf16x8 bB = *(const bf16x8*)(smem + ((kg*2+1)*64 + lane)*8);
      acc0 = __builtin_amdgcn_mfma_f32_16x16x32_bf16(a, bA, acc0, 0, 0, 0);
      acc1 = __builtin_amdgcn_mfma_f32_16x16x32_bf16(a, bB, acc1, 0, 0, 0);
    }

    // ---- assemble i,f,g,o in-lane: lanes n and n^8 swap halves ----
    f32x4 oa = shflx4(acc0, 8), ob = shflx4(acc1, 8);
    f32x4 I = lo ? acc0 : oa;
    f32x4 F = lo ? oa : acc0;
    f32x4 G = lo ? acc1 : ob;
    f32x4 O = lo ? ob : acc1;

    unsigned short* hbw = hbuf + (t&1)*(BATCH*HID);
    #pragma unroll
    for (int u = 0; u < 2; ++u) {
      int rg = rgb + u;
      int bb = b0 + mt*16 + q*4 + rg;
      float kp = kf[(t&1)*BT + mt*16 + q*4 + rg];
      float hr = h_s[u]*kp, cr = c_s[u]*kp;       // state after done-reset
      float iv = sigf (I[rg] + bi);
      float fv = sigf (F[rg] + bf_);
      float gv = tanh_(G[rg] + bg);
      float ov = sigf (O[rg] + bo);
      float cn = fv*cr + iv*gv;
      float hn = ov*tanh_(cn);
      h_s[u] = hn; c_s[u] = cn;
      int j = j0 + r;
      out [(t*BATCH + bb)*HID + j]               = hn;   // lstm_outputs
      hidb[((t*2+0)*BATCH + bb)*HID + j]         = hr;   // hidden_outputs[t][0]
      hidb[((t*2+1)*BATCH + bb)*HID + j]         = cr;   // hidden_outputs[t][1]
      hbw [bb*HID + j]                           = f2bf(hn);
    }

    // stage keeps for t+1 (double-buffered)
    if (t + 1 < T_STEPS && tid < BT)
      kf[((t+1)&1)*BT + tid] = 1.0f - (float)dones[(t+1)*BATCH + b0 + tid];

    __threadfence();
    __syncthreads();
    if (tid == 0)
      __hip_atomic_store(flags + myflag, t + 1,
                         __ATOMIC_RELEASE, __HIP_MEMORY_SCOPE_AGENT);
  }
}

extern "C" void kernel_launch(void* const* d_in, const int* in_sizes, int n_in,
                              void* d_out, int out_size, void* d_ws, size_t ws_size,
                              hipStream_t stream) {
  (void)in_sizes; (void)n_in; (void)out_size; (void)ws_size;
  const float* x   = (const float*)d_in[0];
  const int*   dn  = (const int*)  d_in[1];
  const float* Wih = (const float*)d_in[2];
  const float* Whh = (const float*)d_in[3];
  const float* bih = (const float*)d_in[4];
  const float* bhh = (const float*)d_in[5];
  float* out = (float*)d_out;

  unsigned short* hbuf = (unsigned short*)d_ws;
  size_t hbuf_bytes = (size_t)2*BATCH*HID*sizeof(unsigned short);   // 512 KB
  int* flags = (int*)((char*)d_ws + hbuf_bytes);
  size_t clear_bytes = hbuf_bytes + NWG*sizeof(int);

  hipMemsetAsync(d_ws, 0, clear_bytes, stream);   // zero h(-1) + flags
  hipFuncSetAttribute((const void*)lstm_fused,
                      hipFuncAttributeMaxDynamicSharedMemorySize, LDS_BYTES);
  lstm_fused<<<dim3(NWG), dim3(NTHR), LDS_BYTES, stream>>>(
      x, dn, Wih, Whh, bih, bhh, out, hbuf, flags);
}

// Round 2
// 4138.072 us; speedup vs baseline: 3.3445x; 3.3445x over previous
//
#include <hip/hip_runtime.h>

// LSTM scan, fused x@W_ih.T + h@W_hh.T, bf16 MFMA 16x16x32.
// 256 WGs = 8 batch-groups(32 batches) x 32 members(16 hidden units / 64 gate rows).
// W B-fragments REGISTER-RESIDENT per wave (step-invariant, 256 VGPR).
// Cross-WG h exchange through LLC via RELAXED agent-scope atomics only
// (no acquire/release/threadfence -> no buffer_inv/wbl2 L2-flush storms,
//  which caused round-1's 54 us/step). Ordering = s_waitcnt vmcnt(0) + barrier.

#define T_STEPS 256
#define BATCH   256
#define INP     512
#define HID     512
#define GROUPS  8
#define MEMB    32
#define BT      32          // batches per group
#define NWG     (GROUPS*MEMB)
#define NTHR    256
#define LDS_BYTES (131072 + 2*BT*4)   // 64 rows x 1024 K bf16 pack + keeps[2][BT]

typedef float  f32x4  __attribute__((ext_vector_type(4)));
typedef short  bf16x8 __attribute__((ext_vector_type(8)));

__device__ __forceinline__ unsigned short f2bf(float f) {
  unsigned u = __builtin_bit_cast(unsigned, f);
  return (unsigned short)((u + 0x8000u) >> 16);
}
__device__ __forceinline__ bf16x8 cvt8(float4 a, float4 b) {
  bf16x8 v;
  v[0]=(short)f2bf(a.x); v[1]=(short)f2bf(a.y); v[2]=(short)f2bf(a.z); v[3]=(short)f2bf(a.w);
  v[4]=(short)f2bf(b.x); v[5]=(short)f2bf(b.y); v[6]=(short)f2bf(b.z); v[7]=(short)f2bf(b.w);
  return v;
}
__device__ __forceinline__ float sigf(float x) {
  return __fdividef(1.0f, 1.0f + __expf(-x));
}
__device__ __forceinline__ float tanh_(float x) {
  float e = __expf(-2.0f * fabsf(x));
  float t = __fdividef(1.0f - e, 1.0f + e);
  return copysignf(t, x);
}
__device__ __forceinline__ f32x4 shflx4(f32x4 v, int m) {
  f32x4 r;
  r[0]=__shfl_xor(v[0],m,64); r[1]=__shfl_xor(v[1],m,64);
  r[2]=__shfl_xor(v[2],m,64); r[3]=__shfl_xor(v[3],m,64);
  return r;
}

__global__ void __launch_bounds__(NTHR, 1)
lstm_fused(const float* __restrict__ x, const int* __restrict__ dones,
           const float* __restrict__ Wih, const float* __restrict__ Whh,
           const float* __restrict__ bih, const float* __restrict__ bhh,
           float* __restrict__ out, unsigned* __restrict__ hb32,
           unsigned long long* __restrict__ hb64, int* __restrict__ flags)
{
  extern __shared__ unsigned short smem[];   // [65536] W pack, then keeps
  float* kf = (float*)(smem + 65536);        // keeps[2][BT]

  const int tid  = threadIdx.x;
  const int lane = tid & 63;
  const int wv   = tid >> 6;
  const int grp  = blockIdx.x >> 5;
  const int memb = blockIdx.x & 31;
  const int b0   = grp * BT;
  const int j0   = memb * 16;
  const int mtile = wv & 1;        // which 16-batch M tile
  const int hh    = wv >> 1;       // which hidden octet of the member's 16
  const int q    = lane >> 4;
  const int n    = lane & 15;
  const int r    = n & 7;

  // ---- one-time: W slice (64 gate rows x concat-K 1024) -> LDS, B-frag order
  // frag nf = s>>4: gate-pair gp=nf&1 (0:i/f, 1:g/o), hid octet nf>>1
  // within frag row nn: nn<8 -> first gate, hid nn&7; nn>=8 -> second gate
  for (int e = tid; e < 64*1024; e += NTHR) {
    int s = e >> 10, k = e & 1023;
    int nf = s >> 4, nn = s & 15;
    int gp = nf & 1;
    int hloc = (nf >> 1)*8 + (nn & 7);
    int gate = (nn < 8) ? (gp ? 2 : 0) : (gp ? 3 : 1);
    int grow = gate*HID + j0 + hloc;
    float v = (k < INP) ? Wih[grow*INP + k] : Whh[grow*HID + (k - INP)];
    int kk = k >> 5, qq = (k >> 3) & 3, j = k & 7;
    smem[((kk*4 + nf)*64 + qq*16 + nn)*8 + j] = f2bf(v);
  }
  if (tid < BT) kf[tid] = 1.0f - (float)dones[b0 + tid];
  __syncthreads();

  // ---- B fragments into registers (step-invariant). 64 x bf16x8 = 256 VGPR.
  const int nf0 = 2*hh;
  bf16x8 B0[32], B1[32];
  #pragma unroll
  for (int kk = 0; kk < 32; ++kk) {
    B0[kk] = *(const bf16x8*)(smem + ((kk*4 + nf0    )*64 + lane)*8);
    B1[kk] = *(const bf16x8*)(smem + ((kk*4 + nf0 + 1)*64 + lane)*8);
  }

  const int jmy = j0 + hh*8 + r;   // this lane's hidden unit
  const float bi  = bih[0*HID + jmy] + bhh[0*HID + jmy];
  const float bf_ = bih[1*HID + jmy] + bhh[1*HID + jmy];
  const float bg  = bih[2*HID + jmy] + bhh[2*HID + jmy];
  const float bo  = bih[3*HID + jmy] + bhh[3*HID + jmy];

  float h_s[2] = {0.f, 0.f}, c_s[2] = {0.f, 0.f};
  const bool lo  = (n < 8);
  const int  rgb = lo ? 0 : 2;
  float* hidb = out + (size_t)T_STEPS*BATCH*HID;
  const int bbA = b0 + mtile*16 + n;        // A-row batch for MFMA loads
  const bf16x8 zf = {0,0,0,0,0,0,0,0};

  for (int t = 0; t < T_STEPS; ++t) {
    f32x4 acc0 = {0.f,0.f,0.f,0.f}, acc1 = {0.f,0.f,0.f,0.f};

    // ---- x part: no peer dependence, hides flag latency ----
    const float* xrow = x + (size_t)(t*BATCH + bbA)*INP + q*8;
    #pragma unroll
    for (int kk = 0; kk < 16; ++kk) {
      float4 xa = *(const float4*)(xrow + kk*32);
      float4 xb = *(const float4*)(xrow + kk*32 + 4);
      bf16x8 a = cvt8(xa, xb);
      acc0 = __builtin_amdgcn_mfma_f32_16x16x32_bf16(a, B0[kk], acc0, 0, 0, 0);
      acc1 = __builtin_amdgcn_mfma_f32_16x16x32_bf16(a, B1[kk], acc1, 0, 0, 0);
    }

    // ---- wait for peers' h(t-1): relaxed polls only, no cache maintenance
    if (t > 0) {
      const int* fp = flags + grp*MEMB + lane;
      while (true) {
        int fv = t;
        if (lane < MEMB)
          fv = __hip_atomic_load(fp, __ATOMIC_RELAXED, __HIP_MEMORY_SCOPE_AGENT);
        if (__all(fv >= t)) break;
        __builtin_amdgcn_s_sleep(1);
      }
      asm volatile("" ::: "memory");
    }

    // ---- h part: A rows from LLC (relaxed agent 8B atomics), keep-masked
    const float kpA = kf[(t&1)*BT + mtile*16 + n];
    unsigned long long* hb =
        hb64 + ((t+1)&1)*(BATCH*HID/4) + (size_t)bbA*(HID/4);
    #pragma unroll
    for (int kk = 0; kk < 16; ++kk) {
      union { unsigned long long u[2]; bf16x8 v; } au;
      au.u[0] = __hip_atomic_load(hb + kk*8 + 2*q,     __ATOMIC_RELAXED, __HIP_MEMORY_SCOPE_AGENT);
      au.u[1] = __hip_atomic_load(hb + kk*8 + 2*q + 1, __ATOMIC_RELAXED, __HIP_MEMORY_SCOPE_AGENT);
      bf16x8 a = au.v;
      if (kpA == 0.0f) a = zf;
      acc0 = __builtin_amdgcn_mfma_f32_16x16x32_bf16(a, B0[16+kk], acc0, 0, 0, 0);
      acc1 = __builtin_amdgcn_mfma_f32_16x16x32_bf16(a, B1[16+kk], acc1, 0, 0, 0);
    }

    // ---- gates: lanes n and n^8 swap halves (i,f in acc0; g,o in acc1) ----
    f32x4 oa = shflx4(acc0, 8), ob = shflx4(acc1, 8);
    f32x4 I = lo ? acc0 : oa;
    f32x4 F = lo ? oa : acc0;
    f32x4 G = lo ? acc1 : ob;
    f32x4 O = lo ? ob : acc1;

    float hnv[2];
    #pragma unroll
    for (int u = 0; u < 2; ++u) {
      int rg = rgb + u;
      int lb = mtile*16 + q*4 + rg;
      float kp = kf[(t&1)*BT + lb];
      float hr = h_s[u]*kp, cr = c_s[u]*kp;
      float iv = sigf (I[rg] + bi);
      float fv = sigf (F[rg] + bf_);
      float gv = tanh_(G[rg] + bg);
      float ov = sigf (O[rg] + bo);
      float cn = fv*cr + iv*gv;
      float hn = ov*tanh_(cn);
      h_s[u] = hn; c_s[u] = cn; hnv[u] = hn;
      int bb = b0 + lb;
      out [(size_t)(t*BATCH + bb)*HID + jmy]       = hn;
      hidb[((size_t)(t*2+0)*BATCH + bb)*HID + jmy] = hr;
      hidb[((size_t)(t*2+1)*BATCH + bb)*HID + jmy] = cr;
    }

    // ---- h(t) -> LLC: pair adjacent hids via shfl_xor(1), one dword/lane
    {
      float send  = (n & 1) ? hnv[0] : hnv[1];
      float other = __shfl_xor(send, 1, 64);
      int lb0 = mtile*16 + q*4 + rgb;
      int lbm = (n & 1) ? lb0 + 1 : lb0;
      unsigned lo16 = (n & 1) ? (unsigned)f2bf(other)  : (unsigned)f2bf(hnv[0]);
      unsigned hi16 = (n & 1) ? (unsigned)f2bf(hnv[1]) : (unsigned)f2bf(other);
      unsigned dw = lo16 | (hi16 << 16);
      unsigned* dst = hb32 + (t&1)*(BATCH*HID/2)
                    + (size_t)(b0 + lbm)*(HID/2) + (jmy >> 1);
      __hip_atomic_store(dst, dw, __ATOMIC_RELAXED, __HIP_MEMORY_SCOPE_AGENT);
    }

    // stage keeps for t+1 (other LDS buffer half)
    if (t + 1 < T_STEPS && tid < BT)
      kf[((t+1)&1)*BT + tid] = 1.0f - (float)dones[(t+1)*BATCH + b0 + tid];

    asm volatile("s_waitcnt vmcnt(0)" ::: "memory");  // h stores at LLC
    __syncthreads();                                  // whole WG done
    if (tid == 0)
      __hip_atomic_store(flags + grp*MEMB + memb, t + 1,
                         __ATOMIC_RELAXED, __HIP_MEMORY_SCOPE_AGENT);
  }
}

extern "C" void kernel_launch(void* const* d_in, const int* in_sizes, int n_in,
                              void* d_out, int out_size, void* d_ws, size_t ws_size,
                              hipStream_t stream) {
  (void)in_sizes; (void)n_in; (void)out_size; (void)ws_size;
  const float* x   = (const float*)d_in[0];
  const int*   dn  = (const int*)  d_in[1];
  const float* Wih = (const float*)d_in[2];
  const float* Whh = (const float*)d_in[3];
  const float* bih = (const float*)d_in[4];
  const float* bhh = (const float*)d_in[5];
  float* out = (float*)d_out;

  unsigned*           hb32 = (unsigned*)d_ws;
  unsigned long long* hb64 = (unsigned long long*)d_ws;
  size_t hbuf_bytes = (size_t)2*BATCH*HID*sizeof(unsigned short);   // 512 KB
  int* flags = (int*)((char*)d_ws + hbuf_bytes);
  size_t clear_bytes = hbuf_bytes + NWG*sizeof(int);

  hipMemsetAsync(d_ws, 0, clear_bytes, stream);   // zero h(-1) + flags
  hipFuncSetAttribute((const void*)lstm_fused,
                      hipFuncAttributeMaxDynamicSharedMemorySize, LDS_BYTES);
  lstm_fused<<<dim3(NWG), dim3(NTHR), LDS_BYTES, stream>>>(
      x, dn, Wih, Whh, bih, bhh, out, hb32, hb64, flags);
}